// Round 1
// baseline (65.664 us; speedup 1.0000x reference)
//
#include <hip/hip_runtime.h>
#include <hip/hip_bf16.h>

// NT-Xent (SimCLR) loss: B=4096, D=128, N=8192, TEMP=0.5.
// Plan: normalize rows -> bf16 zn [N][D]; tiled MFMA Gram matrix with fused
// exp-row-sum (swapped operands so row-reduce is lane-local); atomic per-row
// sumexp; finalize scalar.

typedef short bfrag __attribute__((ext_vector_type(8)));   // 8 bf16 (4 VGPRs)
typedef float f32x4 __attribute__((ext_vector_type(4)));

static __device__ __forceinline__ unsigned short f2bf_rne(float x) {
    unsigned u = __float_as_uint(x);
    unsigned r = (u + 0x7fffu + ((u >> 16) & 1u)) >> 16;
    return (unsigned short)r;
}

// ---------------- kernel 1: normalize rows, cast to bf16 -------------------
__global__ __launch_bounds__(256) void nt_normalize(
        const float* __restrict__ zi, const float* __restrict__ zj,
        unsigned short* __restrict__ zn) {
    constexpr int B = 4096, D = 128;
    int wave = threadIdx.x >> 6;
    int lane = threadIdx.x & 63;
    int row  = blockIdx.x * 4 + wave;          // grid = 2048 -> rows 0..8191
    const float* src = (row < B) ? (zi + (size_t)row * D)
                                 : (zj + (size_t)(row - B) * D);
    float2 v = reinterpret_cast<const float2*>(src)[lane];   // 2 elems/lane
    float ss = v.x * v.x + v.y * v.y;
    #pragma unroll
    for (int m = 32; m; m >>= 1) ss += __shfl_xor(ss, m);
    float inv = 1.0f / fmaxf(sqrtf(ss), 1e-8f);
    unsigned short b0 = f2bf_rne(v.x * inv);
    unsigned short b1 = f2bf_rne(v.y * inv);
    unsigned pack = (unsigned)b0 | ((unsigned)b1 << 16);
    reinterpret_cast<unsigned*>(zn + (size_t)row * D)[lane] = pack;
}

// ---------------- kernel 2: 128x128 Gram tiles, fused exp-sum --------------
// grid (64, 64): bj = blockIdx.x (j tile), bi = blockIdx.y (i tile).
// Computes D'[j][i] = mfma(zn_j, zn_i) so each lane's accumulator column is a
// single i; sum over j is lane-local + shfl_xor(16/32).
__global__ __launch_bounds__(256, 2) void nt_gram_tile(
        const unsigned short* __restrict__ zn,
        float* __restrict__ sumexp, float* __restrict__ pos) {
    constexpr int Bh = 4096;
    constexpr int LD = 136;                    // +8 bf16 pad: 272B rows, 16B aligned
    __shared__ short ldsI[128][LD];
    __shared__ short ldsJ[128][LD];

    const int bj = blockIdx.x, bi = blockIdx.y;
    const int tid = threadIdx.x;
    const short* zs = (const short*)zn;

    // stage both tiles: 256 threads, 16B/thread/row-group, 8 iters each
    {
        int r0 = tid >> 4;                     // 0..15
        int c  = (tid & 15) * 8;               // element col, 16B chunks
        #pragma unroll
        for (int rr = 0; rr < 128; rr += 16) {
            int r = rr + r0;
            int4 vi = *reinterpret_cast<const int4*>(zs + ((size_t)(bi * 128 + r)) * 128 + c);
            int4 vj = *reinterpret_cast<const int4*>(zs + ((size_t)(bj * 128 + r)) * 128 + c);
            *reinterpret_cast<int4*>(&ldsI[r][c]) = vi;
            *reinterpret_cast<int4*>(&ldsJ[r][c]) = vj;
        }
    }
    __syncthreads();

    const int wid  = tid >> 6;
    const int lane = tid & 63;
    const int wj = wid >> 1;                   // j half (0..1) -> 64 rows
    const int wi = wid & 1;                    // i half
    const int lr = lane & 15;
    const int lk = lane >> 4;                  // 0..3

    f32x4 acc[4][4] = {};                      // [fj][fi]
    #pragma unroll
    for (int ks = 0; ks < 4; ++ks) {
        const int kb = ks * 32 + lk * 8;       // element offset in K
        bfrag aj[4], ai[4];
        #pragma unroll
        for (int f = 0; f < 4; ++f) {
            aj[f] = *reinterpret_cast<const bfrag*>(&ldsJ[wj * 64 + f * 16 + lr][kb]);
            ai[f] = *reinterpret_cast<const bfrag*>(&ldsI[wi * 64 + f * 16 + lr][kb]);
        }
        #pragma unroll
        for (int fj = 0; fj < 4; ++fj)
            #pragma unroll
            for (int fi = 0; fi < 4; ++fi)
                acc[fj][fi] = __builtin_amdgcn_mfma_f32_16x16x32_bf16(
                    aj[fj], ai[fi], acc[fj][fi], 0, 0, 0);
    }

    // epilogue: val = acc * 2.0 (1/TEMP); e = exp(val) = exp2(acc * 2*log2e)
    constexpr float K_E = 2.8853900817779268f; // 2 * log2(e)
    constexpr float INV_T = 2.0f;
    #pragma unroll
    for (int fi = 0; fi < 4; ++fi) {
        const int ig = bi * 128 + wi * 64 + fi * 16 + lr;
        const int partner = (ig < Bh) ? ig + Bh : ig - Bh;
        float s = 0.f;
        #pragma unroll
        for (int fj = 0; fj < 4; ++fj) {
            const int jbase = bj * 128 + wj * 64 + fj * 16 + lk * 4;
            #pragma unroll
            for (int r = 0; r < 4; ++r) {
                const int jg = jbase + r;
                const float a = acc[fj][fi][r];
                if (jg == partner) pos[ig] = a * INV_T;
                s += (jg == ig) ? 0.f : exp2f(a * K_E);
            }
        }
        s += __shfl_xor(s, 16);
        s += __shfl_xor(s, 32);
        if (lk == 0) atomicAdd(&sumexp[ig], s);   // 16 lanes, consecutive addrs
    }
}

// ---------------- kernel 3: finalize scalar --------------------------------
__global__ __launch_bounds__(256) void nt_finalize(
        const float* __restrict__ sumexp, const float* __restrict__ pos,
        float* __restrict__ out) {
    constexpr int N = 8192;
    float s = 0.f;
    for (int i = threadIdx.x; i < N; i += 256)
        s += __logf(sumexp[i]) - pos[i];
    #pragma unroll
    for (int m = 32; m; m >>= 1) s += __shfl_xor(s, m);
    __shared__ float red[4];
    if ((threadIdx.x & 63) == 0) red[threadIdx.x >> 6] = s;
    __syncthreads();
    if (threadIdx.x == 0)
        out[0] = (red[0] + red[1] + red[2] + red[3]) * (1.0f / (float)N);
}

extern "C" void kernel_launch(void* const* d_in, const int* in_sizes, int n_in,
                              void* d_out, int out_size, void* d_ws, size_t ws_size,
                              hipStream_t stream) {
    const float* zi = (const float*)d_in[0];
    const float* zj = (const float*)d_in[1];
    float* out = (float*)d_out;

    char* ws = (char*)d_ws;
    unsigned short* zn = (unsigned short*)ws;                  // 8192*128*2 = 2 MB
    float* sumexp = (float*)(ws + 2 * 1024 * 1024);            // 32 KB
    float* pos    = (float*)(ws + 2 * 1024 * 1024 + 8192 * 4); // 32 KB

    hipMemsetAsync(sumexp, 0, 8192 * sizeof(float), stream);   // ws is poisoned; zero each launch
    nt_normalize<<<2048, 256, 0, stream>>>(zi, zj, zn);
    nt_gram_tile<<<dim3(64, 64), 256, 0, stream>>>(zn, sumexp, pos);
    nt_finalize<<<1, 256, 0, stream>>>(sumexp, pos, out);
}

// Round 2
// 64.768 us; speedup vs baseline: 1.0138x; 1.0138x over previous
//
#include <hip/hip_runtime.h>
#include <hip/hip_bf16.h>

// NT-Xent (SimCLR) loss: B=4096, D=128, N=8192, TEMP=0.5.
// Round 2: symmetric-pair tiles (2080 blocks, each exp feeds row AND col sums),
// no LDS (fragments direct from L2-resident zn), predicate-free epilogue
// (pos & diag precomputed in the normalize kernel, diag subtracted at finalize).

typedef short bfrag __attribute__((ext_vector_type(8)));   // 8 bf16 (4 VGPRs)
typedef float f32x4 __attribute__((ext_vector_type(4)));

static __device__ __forceinline__ unsigned short f2bf_rne(float x) {
    unsigned u = __float_as_uint(x);
    return (unsigned short)((u + 0x7fffu + ((u >> 16) & 1u)) >> 16);
}
static __device__ __forceinline__ float bf2f(unsigned short b) {
    return __uint_as_float(((unsigned)b) << 16);
}

// ------ kernel 1: normalize pair (i, i+B), emit zn/bf16, diag, pos ---------
__global__ __launch_bounds__(256) void nt_norm_pair(
        const float* __restrict__ zi, const float* __restrict__ zj,
        unsigned short* __restrict__ zn, float* __restrict__ diag,
        float* __restrict__ pos) {
    constexpr int B = 4096, D = 128;
    const int wave = threadIdx.x >> 6, lane = threadIdx.x & 63;
    const int p = blockIdx.x * 4 + wave;                   // 0..4095
    float2 a = reinterpret_cast<const float2*>(zi + (size_t)p * D)[lane];
    float2 b = reinterpret_cast<const float2*>(zj + (size_t)p * D)[lane];
    float sa = a.x * a.x + a.y * a.y;
    float sb = b.x * b.x + b.y * b.y;
    #pragma unroll
    for (int m = 32; m; m >>= 1) { sa += __shfl_xor(sa, m); sb += __shfl_xor(sb, m); }
    float ia = 1.f / fmaxf(sqrtf(sa), 1e-8f);
    float ib = 1.f / fmaxf(sqrtf(sb), 1e-8f);
    unsigned short a0 = f2bf_rne(a.x * ia), a1 = f2bf_rne(a.y * ia);
    unsigned short b0 = f2bf_rne(b.x * ib), b1 = f2bf_rne(b.y * ib);
    float fa0 = bf2f(a0), fa1 = bf2f(a1), fb0 = bf2f(b0), fb1 = bf2f(b1);
    float da = fa0 * fa0 + fa1 * fa1;                      // bf16 self-dot (matches MFMA diag)
    float db = fb0 * fb0 + fb1 * fb1;
    float cr = fa0 * fb0 + fa1 * fb1;                      // bf16 cross-dot (the positive pair)
    #pragma unroll
    for (int m = 32; m; m >>= 1) {
        da += __shfl_xor(da, m); db += __shfl_xor(db, m); cr += __shfl_xor(cr, m);
    }
    reinterpret_cast<unsigned*>(zn + (size_t)p * D)[lane] =
        (unsigned)a0 | ((unsigned)a1 << 16);
    reinterpret_cast<unsigned*>(zn + (size_t)(p + B) * D)[lane] =
        (unsigned)b0 | ((unsigned)b1 << 16);
    if (lane == 0) {
        diag[p] = da; diag[p + B] = db;
        pos[p] = 2.f * cr; pos[p + B] = 2.f * cr;          // sim symmetric
    }
}

// ------ kernel 2: symmetric 128x128 Gram tiles, fused exp-sum, no LDS ------
// grid (64, 33): bi = blockIdx.x, bj = (bi + d) & 63 covers each unordered
// tile pair exactly once (d=32 only for bi<32). acc[fj][fi] = sim[j][i].
__global__ __launch_bounds__(256, 3) void nt_gram_sym(
        const unsigned short* __restrict__ zn, float* __restrict__ sumexp) {
    const int bi = blockIdx.x;
    const int d  = blockIdx.y;
    if (d == 32 && bi >= 32) return;
    const int bj = (bi + d) & 63;
    const bool docol = (d != 0);

    const short* zs = (const short*)zn;
    const int tid = threadIdx.x, wid = tid >> 6, lane = tid & 63;
    const int wj = wid >> 1, wi = wid & 1;
    const int lr = lane & 15, lk = lane >> 4;
    const int ibase = bi * 128 + wi * 64;
    const int jbase = bj * 128 + wj * 64;

    f32x4 acc[4][4] = {};                                  // [fj][fi]
    #pragma unroll
    for (int ks = 0; ks < 4; ++ks) {
        const int kb = ks * 32 + lk * 8;                   // element offset in K
        bfrag aj[4], ai[4];
        #pragma unroll
        for (int f = 0; f < 4; ++f) {
            aj[f] = *reinterpret_cast<const bfrag*>(zs + (size_t)(jbase + f * 16 + lr) * 128 + kb);
            ai[f] = *reinterpret_cast<const bfrag*>(zs + (size_t)(ibase + f * 16 + lr) * 128 + kb);
        }
        #pragma unroll
        for (int fj = 0; fj < 4; ++fj)
            #pragma unroll
            for (int fi = 0; fi < 4; ++fi)
                acc[fj][fi] = __builtin_amdgcn_mfma_f32_16x16x32_bf16(
                    aj[fj], ai[fi], acc[fj][fi], 0, 0, 0);
    }

    // epilogue: e = exp(2*sim) = exp2(acc * 2*log2(e)); diag included (finalize subtracts)
    constexpr float K_E = 2.8853900817779268f;             // 2 * log2(e)
    float jp[16] = {};                                     // col partials [fj*4+r]
    #pragma unroll
    for (int fi = 0; fi < 4; ++fi) {
        float s = 0.f;
        #pragma unroll
        for (int fj = 0; fj < 4; ++fj)
            #pragma unroll
            for (int r = 0; r < 4; ++r) {
                const float e = exp2f(acc[fj][fi][r] * K_E);
                s += e;
                jp[fj * 4 + r] += e;
            }
        s += __shfl_xor(s, 16);
        s += __shfl_xor(s, 32);
        if (lk == 0) atomicAdd(&sumexp[ibase + fi * 16 + lr], s);
    }
    if (docol) {
        float myv = 0.f;
        #pragma unroll
        for (int t = 0; t < 16; ++t) {                     // reduce across lr lanes
            float v = jp[t];
            v += __shfl_xor(v, 1);
            v += __shfl_xor(v, 2);
            v += __shfl_xor(v, 4);
            v += __shfl_xor(v, 8);
            if (lr == t) myv = v;                          // designated writer
        }
        atomicAdd(&sumexp[jbase + (lr >> 2) * 16 + lk * 4 + (lr & 3)], myv);
    }
}

// ------ kernel 3: finalize scalar ------------------------------------------
__global__ __launch_bounds__(256) void nt_finalize(
        const float* __restrict__ sumexp, const float* __restrict__ diag,
        const float* __restrict__ pos, float* __restrict__ out) {
    constexpr int N = 8192;
    constexpr float K_E = 2.8853900817779268f;
    float s = 0.f;
    for (int i = threadIdx.x; i < N; i += 256)
        s += __logf(sumexp[i] - exp2f(diag[i] * K_E)) - pos[i];
    #pragma unroll
    for (int m = 32; m; m >>= 1) s += __shfl_xor(s, m);
    __shared__ float red[4];
    if ((threadIdx.x & 63) == 0) red[threadIdx.x >> 6] = s;
    __syncthreads();
    if (threadIdx.x == 0)
        out[0] = (red[0] + red[1] + red[2] + red[3]) * (1.0f / (float)N);
}

extern "C" void kernel_launch(void* const* d_in, const int* in_sizes, int n_in,
                              void* d_out, int out_size, void* d_ws, size_t ws_size,
                              hipStream_t stream) {
    const float* zi = (const float*)d_in[0];
    const float* zj = (const float*)d_in[1];
    float* out = (float*)d_out;

    char* ws = (char*)d_ws;
    unsigned short* zn = (unsigned short*)ws;                    // 2 MB
    float* sumexp = (float*)(ws + 2 * 1024 * 1024);              // 32 KB
    float* diag   = (float*)(ws + 2 * 1024 * 1024 + 1 * 32768);  // 32 KB
    float* pos    = (float*)(ws + 2 * 1024 * 1024 + 2 * 32768);  // 32 KB

    hipMemsetAsync(sumexp, 0, 8192 * sizeof(float), stream);
    nt_norm_pair<<<1024, 256, 0, stream>>>(zi, zj, zn, diag, pos);
    nt_gram_sym<<<dim3(64, 33), 256, 0, stream>>>(zn, sumexp);
    nt_finalize<<<1, 256, 0, stream>>>(sumexp, diag, pos, out);
}

// Round 4
// 49.526 us; speedup vs baseline: 1.3259x; 1.3078x over previous
//
#include <hip/hip_runtime.h>
#include <hip/hip_bf16.h>

// NT-Xent (SimCLR) loss: B=4096, D=128, N=8192, TEMP=0.5.
// Round 4 (= round 3 resubmit after infra failure): symmetric 64x64 tile
// pairs (8256 blocks), LDS staging via global_load_lds(16B) with XOR-swizzle
// through pre-swizzled global source (LDS dest linear), 5 blocks/CU
// occupancy, one barrier per block.

typedef short bfrag __attribute__((ext_vector_type(8)));   // 8 bf16 (4 VGPRs)
typedef float f32x4 __attribute__((ext_vector_type(4)));

static __device__ __forceinline__ unsigned short f2bf_rne(float x) {
    unsigned u = __float_as_uint(x);
    return (unsigned short)((u + 0x7fffu + ((u >> 16) & 1u)) >> 16);
}
static __device__ __forceinline__ float bf2f(unsigned short b) {
    return __uint_as_float(((unsigned)b) << 16);
}

// ------ kernel 1: normalize pair (i, i+B), emit zn/bf16, diag, pos ---------
__global__ __launch_bounds__(256) void nt_norm_pair(
        const float* __restrict__ zi, const float* __restrict__ zj,
        unsigned short* __restrict__ zn, float* __restrict__ diag,
        float* __restrict__ pos) {
    constexpr int B = 4096, D = 128;
    const int wave = threadIdx.x >> 6, lane = threadIdx.x & 63;
    const int p = blockIdx.x * 4 + wave;                   // 0..4095
    float2 a = reinterpret_cast<const float2*>(zi + (size_t)p * D)[lane];
    float2 b = reinterpret_cast<const float2*>(zj + (size_t)p * D)[lane];
    float sa = a.x * a.x + a.y * a.y;
    float sb = b.x * b.x + b.y * b.y;
    #pragma unroll
    for (int m = 32; m; m >>= 1) { sa += __shfl_xor(sa, m); sb += __shfl_xor(sb, m); }
    float ia = 1.f / fmaxf(sqrtf(sa), 1e-8f);
    float ib = 1.f / fmaxf(sqrtf(sb), 1e-8f);
    unsigned short a0 = f2bf_rne(a.x * ia), a1 = f2bf_rne(a.y * ia);
    unsigned short b0 = f2bf_rne(b.x * ib), b1 = f2bf_rne(b.y * ib);
    float fa0 = bf2f(a0), fa1 = bf2f(a1), fb0 = bf2f(b0), fb1 = bf2f(b1);
    float da = fa0 * fa0 + fa1 * fa1;                      // bf16 self-dot (matches MFMA diag)
    float db = fb0 * fb0 + fb1 * fb1;
    float cr = fa0 * fb0 + fa1 * fb1;                      // bf16 cross-dot (positive pair)
    #pragma unroll
    for (int m = 32; m; m >>= 1) {
        da += __shfl_xor(da, m); db += __shfl_xor(db, m); cr += __shfl_xor(cr, m);
    }
    reinterpret_cast<unsigned*>(zn + (size_t)p * D)[lane] =
        (unsigned)a0 | ((unsigned)a1 << 16);
    reinterpret_cast<unsigned*>(zn + (size_t)(p + B) * D)[lane] =
        (unsigned)b0 | ((unsigned)b1 << 16);
    if (lane == 0) {
        diag[p] = da; diag[p + B] = db;
        pos[p] = 2.f * cr; pos[p + B] = 2.f * cr;          // sim symmetric
    }
}

// ------ kernel 2: symmetric 64x64 Gram tile pairs, LDS-staged --------------
// grid (128, 65): bi = blockIdx.x, bj = (bi + d) & 127 covers each unordered
// 64-tile pair exactly once (d=64 only for bi<64). acc[fj][fi] = sim[j][i].
__global__ __launch_bounds__(256, 5) void nt_gram_sym(
        const unsigned short* __restrict__ zn, float* __restrict__ sumexp) {
    const int bi = blockIdx.x;
    const int d  = blockIdx.y;
    if (d == 64 && bi >= 64) return;
    const int bj = (bi + d) & 127;
    const bool docol = (d != 0);

    __shared__ short lds[2][64][128];                      // [I/J][row][128 bf16] = 32 KB
    const short* zs = (const short*)zn;
    const int tid = threadIdx.x, wid = tid >> 6, lane = tid & 63;

    // stage both tiles: 2048 x 16B chunks; LDS linear, global source
    // pre-swizzled so LDS pos (r, cpos) holds global chunk cpos ^ (r & 7).
    {
        const int rb0 = bi * 64, rb1 = bj * 64;
        #pragma unroll
        for (int q = 0; q < 8; ++q) {
            const int cbase = (q * 4 + wid) * 64;          // wave-uniform chunk base
            const int chunk = cbase + lane;                // 0..2047
            const int t = chunk >> 10;
            const int p = chunk & 1023;
            const int r = p >> 4;
            const int cpos = p & 15;
            const int csrc = cpos ^ (r & 7);
            const short* g = zs + (size_t)((t ? rb1 : rb0) + r) * 128 + csrc * 8;
            __builtin_amdgcn_global_load_lds(
                (const __attribute__((address_space(1))) void*)g,
                (__attribute__((address_space(3))) void*)(&lds[0][0][0] + (size_t)cbase * 8),
                16, 0, 0);
        }
    }
    __syncthreads();                                       // compiler drains vmcnt(0)

    const int wj = wid >> 1, wi = wid & 1;                 // wave -> 32x32 quadrant
    const int lr = lane & 15, lk = lane >> 4;
    const int ibase = bi * 64 + wi * 32;
    const int jbase = bj * 64 + wj * 32;

    f32x4 acc[2][2] = {};                                  // [fj][fi]
    #pragma unroll
    for (int ks = 0; ks < 4; ++ks) {
        const int cc = (ks * 4 + lk) ^ (lr & 7);           // swizzled chunk index
        bfrag aj[2], ai[2];
        #pragma unroll
        for (int f = 0; f < 2; ++f) {
            aj[f] = *reinterpret_cast<const bfrag*>(&lds[1][wj * 32 + f * 16 + lr][cc * 8]);
            ai[f] = *reinterpret_cast<const bfrag*>(&lds[0][wi * 32 + f * 16 + lr][cc * 8]);
        }
        #pragma unroll
        for (int fj = 0; fj < 2; ++fj)
            #pragma unroll
            for (int fi = 0; fi < 2; ++fi)
                acc[fj][fi] = __builtin_amdgcn_mfma_f32_16x16x32_bf16(
                    aj[fj], ai[fi], acc[fj][fi], 0, 0, 0);
    }

    // epilogue: e = exp(2*sim) = exp2(acc * 2*log2(e)); diag subtracted later
    constexpr float K_E = 2.8853900817779268f;             // 2 * log2(e)
    float jp[8] = {};                                      // col partials [fj*4+r]
    #pragma unroll
    for (int fi = 0; fi < 2; ++fi) {
        float s = 0.f;
        #pragma unroll
        for (int fj = 0; fj < 2; ++fj)
            #pragma unroll
            for (int r = 0; r < 4; ++r) {
                const float e = exp2f(acc[fj][fi][r] * K_E);
                s += e;
                jp[fj * 4 + r] += e;
            }
        s += __shfl_xor(s, 16);
        s += __shfl_xor(s, 32);
        if (lk == 0) atomicAdd(&sumexp[ibase + fi * 16 + lr], s);
    }
    if (docol) {                                           // j-row sums via symmetry
        float myv = 0.f;
        #pragma unroll
        for (int t = 0; t < 8; ++t) {
            float v = jp[t];
            v += __shfl_xor(v, 1);
            v += __shfl_xor(v, 2);
            v += __shfl_xor(v, 4);
            v += __shfl_xor(v, 8);
            if (lr == t) myv = v;                          // designated writer
        }
        if (lr < 8)
            atomicAdd(&sumexp[jbase + (lr >> 2) * 16 + lk * 4 + (lr & 3)], myv);
    }
}

// ------ kernel 3: finalize scalar ------------------------------------------
__global__ __launch_bounds__(1024) void nt_finalize(
        const float* __restrict__ sumexp, const float* __restrict__ diag,
        const float* __restrict__ pos, float* __restrict__ out) {
    constexpr int N = 8192;
    constexpr float K_E = 2.8853900817779268f;
    float s = 0.f;
    for (int i = threadIdx.x; i < N; i += 1024)
        s += __logf(sumexp[i] - exp2f(diag[i] * K_E)) - pos[i];
    #pragma unroll
    for (int m = 32; m; m >>= 1) s += __shfl_xor(s, m);
    __shared__ float red[16];
    if ((threadIdx.x & 63) == 0) red[threadIdx.x >> 6] = s;
    __syncthreads();
    if (threadIdx.x == 0) {
        float t = 0.f;
        #pragma unroll
        for (int w = 0; w < 16; ++w) t += red[w];
        out[0] = t * (1.0f / (float)N);
    }
}

extern "C" void kernel_launch(void* const* d_in, const int* in_sizes, int n_in,
                              void* d_out, int out_size, void* d_ws, size_t ws_size,
                              hipStream_t stream) {
    const float* zi = (const float*)d_in[0];
    const float* zj = (const float*)d_in[1];
    float* out = (float*)d_out;

    char* ws = (char*)d_ws;
    unsigned short* zn = (unsigned short*)ws;                    // 2 MB
    float* sumexp = (float*)(ws + 2 * 1024 * 1024);              // 32 KB
    float* diag   = (float*)(ws + 2 * 1024 * 1024 + 1 * 32768);  // 32 KB
    float* pos    = (float*)(ws + 2 * 1024 * 1024 + 2 * 32768);  // 32 KB

    hipMemsetAsync(sumexp, 0, 8192 * sizeof(float), stream);
    nt_norm_pair<<<1024, 256, 0, stream>>>(zi, zj, zn, diag, pos);
    nt_gram_sym<<<dim3(128, 65), 256, 0, stream>>>(zn, sumexp);
    nt_finalize<<<1, 1024, 0, stream>>>(sumexp, diag, pos, out);
}

// Round 5
// 45.370 us; speedup vs baseline: 1.4473x; 1.0916x over previous
//
#include <hip/hip_runtime.h>
#include <hip/hip_bf16.h>

// NT-Xent (SimCLR) loss: B=4096, D=128, N=8192, TEMP=0.5.
// Round 5: drop the hipMemsetAsync (rocclr fillBuffer cost ~40 us/replay!);
// nt_norm_pair zeroes sumexp instead. Gram kernel unchanged from round 4:
// symmetric 64x64 tile pairs, global_load_lds(16B) + XOR swizzle via
// pre-swizzled global source, 5 blocks/CU, one barrier.

typedef short bfrag __attribute__((ext_vector_type(8)));   // 8 bf16 (4 VGPRs)
typedef float f32x4 __attribute__((ext_vector_type(4)));

static __device__ __forceinline__ unsigned short f2bf_rne(float x) {
    unsigned u = __float_as_uint(x);
    return (unsigned short)((u + 0x7fffu + ((u >> 16) & 1u)) >> 16);
}
static __device__ __forceinline__ float bf2f(unsigned short b) {
    return __uint_as_float(((unsigned)b) << 16);
}

// ------ kernel 1: normalize pair (i, i+B), emit zn/bf16, diag, pos, zero sumexp
__global__ __launch_bounds__(256) void nt_norm_pair(
        const float* __restrict__ zi, const float* __restrict__ zj,
        unsigned short* __restrict__ zn, float* __restrict__ diag,
        float* __restrict__ pos, float* __restrict__ sumexp) {
    constexpr int B = 4096, D = 128;
    const int wave = threadIdx.x >> 6, lane = threadIdx.x & 63;
    const int p = blockIdx.x * 4 + wave;                   // 0..4095
    float2 a = reinterpret_cast<const float2*>(zi + (size_t)p * D)[lane];
    float2 b = reinterpret_cast<const float2*>(zj + (size_t)p * D)[lane];
    float sa = a.x * a.x + a.y * a.y;
    float sb = b.x * b.x + b.y * b.y;
    #pragma unroll
    for (int m = 32; m; m >>= 1) { sa += __shfl_xor(sa, m); sb += __shfl_xor(sb, m); }
    float ia = 1.f / fmaxf(sqrtf(sa), 1e-8f);
    float ib = 1.f / fmaxf(sqrtf(sb), 1e-8f);
    unsigned short a0 = f2bf_rne(a.x * ia), a1 = f2bf_rne(a.y * ia);
    unsigned short b0 = f2bf_rne(b.x * ib), b1 = f2bf_rne(b.y * ib);
    float fa0 = bf2f(a0), fa1 = bf2f(a1), fb0 = bf2f(b0), fb1 = bf2f(b1);
    float da = fa0 * fa0 + fa1 * fa1;                      // bf16 self-dot (matches MFMA diag)
    float db = fb0 * fb0 + fb1 * fb1;
    float cr = fa0 * fb0 + fa1 * fb1;                      // bf16 cross-dot (positive pair)
    #pragma unroll
    for (int m = 32; m; m >>= 1) {
        da += __shfl_xor(da, m); db += __shfl_xor(db, m); cr += __shfl_xor(cr, m);
    }
    reinterpret_cast<unsigned*>(zn + (size_t)p * D)[lane] =
        (unsigned)a0 | ((unsigned)a1 << 16);
    reinterpret_cast<unsigned*>(zn + (size_t)(p + B) * D)[lane] =
        (unsigned)b0 | ((unsigned)b1 << 16);
    if (lane == 0) {
        diag[p] = da; diag[p + B] = db;
        pos[p] = 2.f * cr; pos[p + B] = 2.f * cr;          // sim symmetric
        sumexp[p] = 0.f; sumexp[p + B] = 0.f;              // replaces hipMemsetAsync
    }
}

// ------ kernel 2: symmetric 64x64 Gram tile pairs, LDS-staged --------------
// grid (128, 65): bi = blockIdx.x, bj = (bi + d) & 127 covers each unordered
// 64-tile pair exactly once (d=64 only for bi<64). acc[fj][fi] = sim[j][i].
__global__ __launch_bounds__(256, 5) void nt_gram_sym(
        const unsigned short* __restrict__ zn, float* __restrict__ sumexp) {
    const int bi = blockIdx.x;
    const int d  = blockIdx.y;
    if (d == 64 && bi >= 64) return;
    const int bj = (bi + d) & 127;
    const bool docol = (d != 0);

    __shared__ short lds[2][64][128];                      // [I/J][row][128 bf16] = 32 KB
    const short* zs = (const short*)zn;
    const int tid = threadIdx.x, wid = tid >> 6, lane = tid & 63;

    // stage both tiles: 2048 x 16B chunks; LDS linear, global source
    // pre-swizzled so LDS pos (r, cpos) holds global chunk cpos ^ (r & 7).
    {
        const int rb0 = bi * 64, rb1 = bj * 64;
        #pragma unroll
        for (int q = 0; q < 8; ++q) {
            const int cbase = (q * 4 + wid) * 64;          // wave-uniform chunk base
            const int chunk = cbase + lane;                // 0..2047
            const int t = chunk >> 10;
            const int p = chunk & 1023;
            const int r = p >> 4;
            const int cpos = p & 15;
            const int csrc = cpos ^ (r & 7);
            const short* g = zs + (size_t)((t ? rb1 : rb0) + r) * 128 + csrc * 8;
            __builtin_amdgcn_global_load_lds(
                (const __attribute__((address_space(1))) void*)g,
                (__attribute__((address_space(3))) void*)(&lds[0][0][0] + (size_t)cbase * 8),
                16, 0, 0);
        }
    }
    __syncthreads();                                       // compiler drains vmcnt(0)

    const int wj = wid >> 1, wi = wid & 1;                 // wave -> 32x32 quadrant
    const int lr = lane & 15, lk = lane >> 4;
    const int ibase = bi * 64 + wi * 32;
    const int jbase = bj * 64 + wj * 32;

    f32x4 acc[2][2] = {};                                  // [fj][fi]
    #pragma unroll
    for (int ks = 0; ks < 4; ++ks) {
        const int cc = (ks * 4 + lk) ^ (lr & 7);           // swizzled chunk index
        bfrag aj[2], ai[2];
        #pragma unroll
        for (int f = 0; f < 2; ++f) {
            aj[f] = *reinterpret_cast<const bfrag*>(&lds[1][wj * 32 + f * 16 + lr][cc * 8]);
            ai[f] = *reinterpret_cast<const bfrag*>(&lds[0][wi * 32 + f * 16 + lr][cc * 8]);
        }
        #pragma unroll
        for (int fj = 0; fj < 2; ++fj)
            #pragma unroll
            for (int fi = 0; fi < 2; ++fi)
                acc[fj][fi] = __builtin_amdgcn_mfma_f32_16x16x32_bf16(
                    aj[fj], ai[fi], acc[fj][fi], 0, 0, 0);
    }

    // epilogue: e = exp(2*sim) = exp2(acc * 2*log2(e)); diag subtracted later
    constexpr float K_E = 2.8853900817779268f;             // 2 * log2(e)
    float jp[8] = {};                                      // col partials [fj*4+r]
    #pragma unroll
    for (int fi = 0; fi < 2; ++fi) {
        float s = 0.f;
        #pragma unroll
        for (int fj = 0; fj < 2; ++fj)
            #pragma unroll
            for (int r = 0; r < 4; ++r) {
                const float e = exp2f(acc[fj][fi][r] * K_E);
                s += e;
                jp[fj * 4 + r] += e;
            }
        s += __shfl_xor(s, 16);
        s += __shfl_xor(s, 32);
        if (lk == 0) atomicAdd(&sumexp[ibase + fi * 16 + lr], s);
    }
    if (docol) {                                           // j-row sums via symmetry
        float myv = 0.f;
        #pragma unroll
        for (int t = 0; t < 8; ++t) {
            float v = jp[t];
            v += __shfl_xor(v, 1);
            v += __shfl_xor(v, 2);
            v += __shfl_xor(v, 4);
            v += __shfl_xor(v, 8);
            if (lr == t) myv = v;                          // designated writer
        }
        if (lr < 8)
            atomicAdd(&sumexp[jbase + (lr >> 2) * 16 + lk * 4 + (lr & 3)], myv);
    }
}

// ------ kernel 3: finalize scalar ------------------------------------------
__global__ __launch_bounds__(1024) void nt_finalize(
        const float* __restrict__ sumexp, const float* __restrict__ diag,
        const float* __restrict__ pos, float* __restrict__ out) {
    constexpr int N = 8192;
    constexpr float K_E = 2.8853900817779268f;
    float s = 0.f;
    for (int i = threadIdx.x; i < N; i += 1024)
        s += __logf(sumexp[i] - exp2f(diag[i] * K_E)) - pos[i];
    #pragma unroll
    for (int m = 32; m; m >>= 1) s += __shfl_xor(s, m);
    __shared__ float red[16];
    if ((threadIdx.x & 63) == 0) red[threadIdx.x >> 6] = s;
    __syncthreads();
    if (threadIdx.x == 0) {
        float t = 0.f;
        #pragma unroll
        for (int w = 0; w < 16; ++w) t += red[w];
        out[0] = t * (1.0f / (float)N);
    }
}

extern "C" void kernel_launch(void* const* d_in, const int* in_sizes, int n_in,
                              void* d_out, int out_size, void* d_ws, size_t ws_size,
                              hipStream_t stream) {
    const float* zi = (const float*)d_in[0];
    const float* zj = (const float*)d_in[1];
    float* out = (float*)d_out;

    char* ws = (char*)d_ws;
    unsigned short* zn = (unsigned short*)ws;                    // 2 MB
    float* sumexp = (float*)(ws + 2 * 1024 * 1024);              // 32 KB
    float* diag   = (float*)(ws + 2 * 1024 * 1024 + 1 * 32768);  // 32 KB
    float* pos    = (float*)(ws + 2 * 1024 * 1024 + 2 * 32768);  // 32 KB

    nt_norm_pair<<<1024, 256, 0, stream>>>(zi, zj, zn, diag, pos, sumexp);
    nt_gram_sym<<<dim3(128, 65), 256, 0, stream>>>(zn, sumexp);
    nt_finalize<<<1, 1024, 0, stream>>>(sumexp, diag, pos, out);
}

// Round 6
// 36.416 us; speedup vs baseline: 1.8032x; 1.2459x over previous
//
#include <hip/hip_runtime.h>
#include <hip/hip_bf16.h>

// NT-Xent (SimCLR) loss: B=4096, D=128, N=8192, TEMP=0.5.
// Round 6: strip-mined symmetric gram. Each block caches one 64-row tile in
// registers (MFMA A-operand, direct from L2) and streams 4 partner tiles
// through double-buffered LDS (global_load_lds 16B + XOR swizzle, counted
// vmcnt(4), raw s_barrier). j-col (A-side) sums accumulate in registers
// across the strip -> 32-shfl reduce once per block. i-row sums per tile
// (cheap: 2 shfl + atomic). 2112 blocks, 32KB LDS, 4 blocks/CU.

typedef short bfrag __attribute__((ext_vector_type(8)));   // 8 bf16 (4 VGPRs)
typedef float f32x4 __attribute__((ext_vector_type(4)));

static __device__ __forceinline__ unsigned short f2bf_rne(float x) {
    unsigned u = __float_as_uint(x);
    return (unsigned short)((u + 0x7fffu + ((u >> 16) & 1u)) >> 16);
}
static __device__ __forceinline__ float bf2f(unsigned short b) {
    return __uint_as_float(((unsigned)b) << 16);
}

// ------ kernel 1: normalize pair (i, i+B), emit zn/bf16, diag, pos, zero sumexp
__global__ __launch_bounds__(256) void nt_norm_pair(
        const float* __restrict__ zi, const float* __restrict__ zj,
        unsigned short* __restrict__ zn, float* __restrict__ diag,
        float* __restrict__ pos, float* __restrict__ sumexp) {
    constexpr int B = 4096, D = 128;
    const int wave = threadIdx.x >> 6, lane = threadIdx.x & 63;
    const int p = blockIdx.x * 4 + wave;                   // 0..4095
    float2 a = reinterpret_cast<const float2*>(zi + (size_t)p * D)[lane];
    float2 b = reinterpret_cast<const float2*>(zj + (size_t)p * D)[lane];
    float sa = a.x * a.x + a.y * a.y;
    float sb = b.x * b.x + b.y * b.y;
    #pragma unroll
    for (int m = 32; m; m >>= 1) { sa += __shfl_xor(sa, m); sb += __shfl_xor(sb, m); }
    float ia = 1.f / fmaxf(sqrtf(sa), 1e-8f);
    float ib = 1.f / fmaxf(sqrtf(sb), 1e-8f);
    unsigned short a0 = f2bf_rne(a.x * ia), a1 = f2bf_rne(a.y * ia);
    unsigned short b0 = f2bf_rne(b.x * ib), b1 = f2bf_rne(b.y * ib);
    float fa0 = bf2f(a0), fa1 = bf2f(a1), fb0 = bf2f(b0), fb1 = bf2f(b1);
    float da = fa0 * fa0 + fa1 * fa1;                      // bf16 self-dot (matches MFMA diag)
    float db = fb0 * fb0 + fb1 * fb1;
    float cr = fa0 * fb0 + fa1 * fb1;                      // bf16 cross-dot (positive pair)
    #pragma unroll
    for (int m = 32; m; m >>= 1) {
        da += __shfl_xor(da, m); db += __shfl_xor(db, m); cr += __shfl_xor(cr, m);
    }
    reinterpret_cast<unsigned*>(zn + (size_t)p * D)[lane] =
        (unsigned)a0 | ((unsigned)a1 << 16);
    reinterpret_cast<unsigned*>(zn + (size_t)(p + B) * D)[lane] =
        (unsigned)b0 | ((unsigned)b1 << 16);
    if (lane == 0) {
        diag[p] = da; diag[p + B] = db;
        pos[p] = 2.f * cr; pos[p + B] = 2.f * cr;          // sim symmetric
        sumexp[p] = 0.f; sumexp[p + B] = 0.f;              // replaces hipMemsetAsync
    }
}

// ------ kernel 2: strip-mined symmetric gram ------------------------------
// grid (128, 17): cached tile c = blockIdx.x; y<16: streamed tiles at
// d = 4y+t (t=0..3); y==16 (c<64 only): single tile d=64. Each unordered
// tile pair appears exactly once. acc[fj][fi] = sim[j in cached][i in streamed].
__global__ __launch_bounds__(256, 4) void nt_gram_sym(
        const unsigned short* __restrict__ zn, float* __restrict__ sumexp) {
    const int c = blockIdx.x;
    const int y = blockIdx.y;
    if (y == 16 && c >= 64) return;
    const int T  = (y == 16) ? 1 : 4;
    const int d0 = (y == 16) ? 64 : 4 * y;

    __shared__ short buf[2][64][128];                      // 2 x 16 KB stream buffers

    const short* zs = (const short*)zn;
    const int tid = threadIdx.x, wid = tid >> 6, lane = tid & 63;
    const int wj = wid >> 1, wi = wid & 1;                 // wave quadrant
    const int lr = lane & 15, lk = lane >> 4;

    // cached A-frags (tile c, this wave's 32 j-rows), direct from L2
    bfrag ca[4][2];
    {
        const int rbase = c * 64 + wj * 32;
        #pragma unroll
        for (int ks = 0; ks < 4; ++ks)
            #pragma unroll
            for (int f = 0; f < 2; ++f)
                ca[ks][f] = *reinterpret_cast<const bfrag*>(
                    zs + (size_t)(rbase + f * 16 + lr) * 128 + ks * 32 + lk * 8);
    }

    // stage streamed tile t into buf[slot]: 1024 x 16B chunks, 4 per thread.
    // LDS linear; global source pre-swizzled: LDS (r, cpos) holds chunk cpos^(r&7).
    auto STAGE = [&](int t, int slot) {
        const int srow = ((c + d0 + t) & 127) * 64;
        #pragma unroll
        for (int q = 0; q < 4; ++q) {
            const int cbase = q * 256 + wid * 64;          // wave-uniform
            const int chunk = cbase + lane;                // 0..1023
            const int r = chunk >> 4;
            const int cpos = chunk & 15;
            const int csrc = cpos ^ (r & 7);
            const short* g = zs + (size_t)(srow + r) * 128 + csrc * 8;
            __builtin_amdgcn_global_load_lds(
                (const __attribute__((address_space(1))) void*)g,
                (__attribute__((address_space(3))) void*)(
                    &buf[slot][0][0] + (size_t)cbase * 8),
                16, 0, 0);
        }
    };

    STAGE(0, 0);

    constexpr float K_E = 2.8853900817779268f;             // 2 * log2(e)
    float jp[8] = {0.f, 0.f, 0.f, 0.f, 0.f, 0.f, 0.f, 0.f};

    for (int t = 0; t < T; ++t) {
        if (t + 1 < T) {
            STAGE(t + 1, (t + 1) & 1);
            asm volatile("s_waitcnt vmcnt(4)" ::: "memory");   // buf[t] done, t+1 in flight
        } else {
            asm volatile("s_waitcnt vmcnt(0)" ::: "memory");
        }
        __builtin_amdgcn_s_barrier();

        // ---- compute tile t from buf[t&1] ----
        const int sb = ((c + d0 + t) & 127) * 64;          // streamed base row (i side)
        f32x4 acc[2][2] = {};                              // [fj][fi]
        #pragma unroll
        for (int ks = 0; ks < 4; ++ks) {
            bfrag cb[2];
            #pragma unroll
            for (int f = 0; f < 2; ++f) {
                const int r = wi * 32 + f * 16 + lr;
                const int cc = (ks * 4 + lk) ^ (lr & 7);   // swizzled chunk index
                cb[f] = *reinterpret_cast<const bfrag*>(&buf[t & 1][r][cc * 8]);
            }
            #pragma unroll
            for (int fj = 0; fj < 2; ++fj)
                #pragma unroll
                for (int fi = 0; fi < 2; ++fi)
                    acc[fj][fi] = __builtin_amdgcn_mfma_f32_16x16x32_bf16(
                        ca[ks][fj], cb[fi], acc[fj][fi], 0, 0, 0);
        }

        const float cw = (d0 + t) ? 1.f : 0.f;             // self-tile: no col weight
        #pragma unroll
        for (int fi = 0; fi < 2; ++fi) {
            float s = 0.f;
            #pragma unroll
            for (int fj = 0; fj < 2; ++fj)
                #pragma unroll
                for (int r = 0; r < 4; ++r) {
                    const float e = exp2f(acc[fj][fi][r] * K_E);
                    s += e;
                    jp[fj * 4 + r] += e * cw;              // j-col partial (reg, whole strip)
                }
            s += __shfl_xor(s, 16);                        // i-row sum over lk groups
            s += __shfl_xor(s, 32);
            if (lk == 0) atomicAdd(&sumexp[sb + wi * 32 + fi * 16 + lr], s);
        }
        __builtin_amdgcn_s_barrier();                      // all waves done with buf[t&1]
    }

    // ---- once per block: reduce j-col partials over 16 lr lanes ----
    float myv = 0.f;
    #pragma unroll
    for (int tt = 0; tt < 8; ++tt) {
        float v = jp[tt];
        v += __shfl_xor(v, 1);
        v += __shfl_xor(v, 2);
        v += __shfl_xor(v, 4);
        v += __shfl_xor(v, 8);
        if (lr == tt) myv = v;                             // designated writer
    }
    if (lr < 8)
        atomicAdd(&sumexp[c * 64 + wj * 32 + (lr >> 2) * 16 + lk * 4 + (lr & 3)], myv);
}

// ------ kernel 3: finalize scalar ------------------------------------------
__global__ __launch_bounds__(1024) void nt_finalize(
        const float* __restrict__ sumexp, const float* __restrict__ diag,
        const float* __restrict__ pos, float* __restrict__ out) {
    constexpr int N = 8192;
    constexpr float K_E = 2.8853900817779268f;
    float s = 0.f;
    for (int i = threadIdx.x; i < N; i += 1024)
        s += __logf(sumexp[i] - exp2f(diag[i] * K_E)) - pos[i];
    #pragma unroll
    for (int m = 32; m; m >>= 1) s += __shfl_xor(s, m);
    __shared__ float red[16];
    if ((threadIdx.x & 63) == 0) red[threadIdx.x >> 6] = s;
    __syncthreads();
    if (threadIdx.x == 0) {
        float t = 0.f;
        #pragma unroll
        for (int w = 0; w < 16; ++w) t += red[w];
        out[0] = t * (1.0f / (float)N);
    }
}

extern "C" void kernel_launch(void* const* d_in, const int* in_sizes, int n_in,
                              void* d_out, int out_size, void* d_ws, size_t ws_size,
                              hipStream_t stream) {
    const float* zi = (const float*)d_in[0];
    const float* zj = (const float*)d_in[1];
    float* out = (float*)d_out;

    char* ws = (char*)d_ws;
    unsigned short* zn = (unsigned short*)ws;                    // 2 MB
    float* sumexp = (float*)(ws + 2 * 1024 * 1024);              // 32 KB
    float* diag   = (float*)(ws + 2 * 1024 * 1024 + 1 * 32768);  // 32 KB
    float* pos    = (float*)(ws + 2 * 1024 * 1024 + 2 * 32768);  // 32 KB

    nt_norm_pair<<<1024, 256, 0, stream>>>(zi, zj, zn, diag, pos, sumexp);
    nt_gram_sym<<<dim3(128, 17), 256, 0, stream>>>(zn, sumexp);
    nt_finalize<<<1, 1024, 0, stream>>>(sumexp, diag, pos, out);
}